// Round 16
// baseline (106.090 us; speedup 1.0000x reference)
//
#include <hip/hip_runtime.h>
#include <hip/hip_bf16.h>
#include <cmath>

#define Bn 4
#define Hn 32
#define Qn 64
#define Dn 128
#define Tn 4096
#define Rn 128
#define NTHREADS 512
#define SCALE_QK 0.08838834764831845f
#define NUNITS 66      // 64 quantized KV tiles of 64 + 2 residual tiles
#define DEFER_THR 8.0f

typedef __attribute__((ext_vector_type(8))) short short8;
typedef __attribute__((ext_vector_type(4))) float f32x4;

__device__ __forceinline__ unsigned pk2(float a, float b) {
    __hip_bfloat162 h = __float22bfloat162_rn(make_float2(a, b));
    unsigned u; __builtin_memcpy(&u, &h, 4); return u;
}
__device__ __forceinline__ short8 pack8(float4 f0, float4 f1) {
    unsigned u[4] = { pk2(f0.x,f0.y), pk2(f0.z,f0.w), pk2(f1.x,f1.y), pk2(f1.z,f1.w) };
    short8 s; __builtin_memcpy(&s, u, 16); return s;
}
__device__ __forceinline__ float dq1(unsigned c, int j, float s, float m) {
    return (float)((c >> (4 * j)) & 15u) * s + m;
}

// R15 structure (best: 104.70 us). ONE delta: the stage-next block is hoisted
// from post-PV to post-QK -- the dequant VALU issues under QK-MFMA latency and
// the DS writes drain under softmax's VALU phase, instead of sitting exposed
// right before the barrier. (Compiler can't do this itself: XOR-addressed char*
// stores can't be proven non-aliasing with the LDS reads.)
// 8 fat waves: th = w&1, qh = (w>>1)&1 (32 q), ds = (w>>2)&1 (PV d-half).
// LDS: dbuf 2x32KB (K [64t][128d] 256B rows, key ((t>>3)&3|(t&1)<<2)<<4;
//      V^T [128d][64t] 128B rows, key ((d&7)^((d>>3)&7))<<4)  -- R9-verified.
template<int NS>
__global__ __launch_bounds__(NTHREADS, 2)
void kivi_attn(const float* __restrict__ qry,
               const int*   __restrict__ kcode,
               const float* __restrict__ kscale,
               const float* __restrict__ kmn,
               const float* __restrict__ kfull,
               const int*   __restrict__ vcode,
               const float* __restrict__ vscale,
               const float* __restrict__ vmn,
               const float* __restrict__ vfull,
               float* __restrict__ out,
               float* __restrict__ ws)
{
    __shared__ __align__(16) char SMEM[65536];

    const int tid = threadIdx.x;
    const int bh  = blockIdx.x / NS;
    const int sp  = blockIdx.x % NS;
    const int pb  = bh * NS + sp;
    const int ulo = (sp * NUNITS) / NS;
    const int uhi = ((sp + 1) * NUNITS) / NS;

    const int*   kc  = kcode  + (size_t)bh * (Dn * (Tn / 8));
    const float* ksc = kscale + (size_t)bh * (Dn * (Tn / 32));
    const float* kmm = kmn    + (size_t)bh * (Dn * (Tn / 32));
    const float* kf  = kfull  + (size_t)bh * (Rn * Dn);
    const int*   vc  = vcode  + (size_t)bh * (Tn * (Dn / 8));
    const float* vsc = vscale + (size_t)bh * (Tn * (Dn / 32));
    const float* vmm = vmn    + (size_t)bh * (Tn * (Dn / 32));
    const float* vf  = vfull  + (size_t)bh * (Rn * Dn);

    const int w    = tid >> 6;        // wave 0..7
    const int lane = tid & 63;
    const int th   = w & 1;           // t-half
    const int qh   = (w >> 1) & 1;    // q-half (32 q)
    const int ds   = (w >> 2) & 1;    // PV d-half
    const int g    = lane >> 4;
    const int r    = lane & 15;

    // stage duty: tid<256 K, tid>=256 V
    const bool kduty = (tid < 256);
    const int  tw  = tid & 7,  dg = (tid >> 3) & 31;   // K: t-octet, d-quad
    const int  vwd = tid & 15, tq = (tid >> 4) & 15;   // V: d-octet, t-quad

    // ---- Q B-fragments (scale baked in): 2 q-tiles, cols q = 32qh + 16qt + r ----
    short8 qb[4][2];
    #pragma unroll
    for (int qt = 0; qt < 2; ++qt) {
        const float* qrow = qry + ((size_t)bh * Qn + (32 * qh + 16 * qt + r)) * Dn;
        #pragma unroll
        for (int m = 0; m < 4; ++m) {
            float4 f0 = *(const float4*)(qrow + m * 32 + 8 * g);
            float4 f1 = *(const float4*)(qrow + m * 32 + 8 * g + 4);
            f0.x *= SCALE_QK; f0.y *= SCALE_QK; f0.z *= SCALE_QK; f0.w *= SCALE_QK;
            f1.x *= SCALE_QK; f1.y *= SCALE_QK; f1.z *= SCALE_QK; f1.w *= SCALE_QK;
            qb[m][qt] = pack8(f0, f1);
        }
    }

    // ---- permuted QK A-row mapping (R9-verified): s0/s1 regs <-> t = 32th+8g+{0..7}
    const int t0p  = 32 * th + 8 * (r >> 2) + (r & 3);
    const int kkey = (((r >> 2) | ((r & 1) << 2)) << 4);   // key(t0p) == key(t0p+4)
    const int kb0  = (t0p << 8) + (g << 4);
    const int kb1  = kb0 + (4 << 8);

    f32x4 o[4][2];
    #pragma unroll
    for (int nd = 0; nd < 4; ++nd) {
        o[nd][0] = (f32x4){0.f, 0.f, 0.f, 0.f};
        o[nd][1] = (f32x4){0.f, 0.f, 0.f, 0.f};
    }
    float m_run = -INFINITY;          // wave-uniform
    float lr0 = 0.f, lr1 = 0.f;       // per-lane partials (g-reduced at epilogue)

    // ---- union'd prefetch (4 codes + 4 scales + 4 mins per duty) ----
    const int* cp; const float* scp; const float* mnp;
    int cstr, sstr, cinc, sinc;
    if (kduty) {
        cp  = kc  + (size_t)(4 * dg) * (Tn / 8)  + ulo * 8 + tw;
        scp = ksc + (size_t)(4 * dg) * (Tn / 32) + ulo * 2 + (tw >> 2);
        mnp = kmm + (size_t)(4 * dg) * (Tn / 32) + ulo * 2 + (tw >> 2);
        cstr = Tn / 8;  sstr = Tn / 32;  cinc = 8;  sinc = 2;
    } else {
        cp  = vc  + ((size_t)ulo * 64 + 4 * tq) * (Dn / 8)  + vwd;
        scp = vsc + ((size_t)ulo * 64 + 4 * tq) * (Dn / 32) + (vwd >> 2);
        mnp = vmm + ((size_t)ulo * 64 + 4 * tq) * (Dn / 32) + (vwd >> 2);
        cstr = Dn / 8;  sstr = Dn / 32;
        cinc = 64 * (Dn / 8);  sinc = 64 * (Dn / 32);
    }
    unsigned cc4[4]; float sc4[4], mn4[4];
    auto pfb = [&]() {
        #pragma unroll
        for (int i = 0; i < 4; ++i) {
            cc4[i] = (unsigned)cp[i * cstr];
            sc4[i] = scp[i * sstr];
            mn4[i] = mnp[i * sstr];
        }
        cp += cinc; scp += sinc; mnp += sinc;
    };

    auto stage_quant = [&](char* Kb, char* Vb) {
        if (kduty) {
            // 4 d (=4dg..+3) x 8 t (octet tw): one b64 (4 bf16 along d) per t
            #pragma unroll
            for (int j = 0; j < 8; ++j) {
                int t = 8 * tw + j;
                int key = (((tw & 3) | ((j & 1) << 2)) << 4);
                float v0 = dq1(cc4[0], j, sc4[0], mn4[0]);
                float v1 = dq1(cc4[1], j, sc4[1], mn4[1]);
                float v2 = dq1(cc4[2], j, sc4[2], mn4[2]);
                float v3 = dq1(cc4[3], j, sc4[3], mn4[3]);
                unsigned long long pk = (unsigned long long)pk2(v0, v1)
                                      | ((unsigned long long)pk2(v2, v3) << 32);
                *(unsigned long long*)(Kb + (((t << 8) + 8 * dg) ^ key)) = pk;
            }
        } else {
            // 8 d (octet vwd) x 4 t (=4tq..+3): one b64 (4 bf16 along t) per d
            #pragma unroll
            for (int i = 0; i < 8; ++i) {
                int d = 8 * vwd + i;
                int key = ((i ^ (vwd & 7)) << 4);
                float v0 = dq1(cc4[0], i, sc4[0], mn4[0]);
                float v1 = dq1(cc4[1], i, sc4[1], mn4[1]);
                float v2 = dq1(cc4[2], i, sc4[2], mn4[2]);
                float v3 = dq1(cc4[3], i, sc4[3], mn4[3]);
                unsigned long long pk = (unsigned long long)pk2(v0, v1)
                                      | ((unsigned long long)pk2(v2, v3) << 32);
                *(unsigned long long*)(Vb + (((d << 7) + 8 * tq) ^ key)) = pk;
            }
        }
    };
    auto stage_resid = [&](int rt, char* Kb, char* Vb) {
        {   // K residual fp32 (R9-verbatim, 512 threads)
            int t = tid & 63, dgr = tid >> 6;
            const float* kr = kf + (size_t)(rt * 64 + t) * Dn + dgr * 16;
            int key = (((t >> 3) & 3) | ((t & 1) << 2)) << 4;
            #pragma unroll
            for (int s2 = 0; s2 < 2; ++s2) {
                float4 f0 = *(const float4*)(kr + s2 * 8);
                float4 f1 = *(const float4*)(kr + s2 * 8 + 4);
                *(short8*)(Kb + (((t << 8) + dgr * 32 + s2 * 16) ^ key)) = pack8(f0, f1);
            }
        }
        {   // V residual fp32 transposed gather (R9-verbatim)
            int d = tid & 127, t4 = tid >> 7;
            const float* vr = vf + (size_t)(rt * 64 + t4 * 16) * Dn + d;
            int key = ((d & 7) ^ ((d >> 3) & 7)) << 4;
            #pragma unroll
            for (int s2 = 0; s2 < 2; ++s2) {
                float4 f0, f1;
                f0.x = vr[(size_t)(s2 * 8 + 0) * Dn]; f0.y = vr[(size_t)(s2 * 8 + 1) * Dn];
                f0.z = vr[(size_t)(s2 * 8 + 2) * Dn]; f0.w = vr[(size_t)(s2 * 8 + 3) * Dn];
                f1.x = vr[(size_t)(s2 * 8 + 4) * Dn]; f1.y = vr[(size_t)(s2 * 8 + 5) * Dn];
                f1.z = vr[(size_t)(s2 * 8 + 6) * Dn]; f1.w = vr[(size_t)(s2 * 8 + 7) * Dn];
                *(short8*)(Vb + (((d << 7) + t4 * 32 + s2 * 16) ^ key)) = pack8(f0, f1);
            }
        }
    };

    // ---- prologue: stage unit ulo into buf0 (ulo < 64 always for NS<=4) ----
    pfb();
    stage_quant(SMEM, SMEM + 16384);
    if (ulo + 1 < uhi && ulo + 1 < 64) pfb();
    __syncthreads();

    for (int u = ulo; u < uhi; ++u) {
        const int cur = (u - ulo) & 1;
        char* Kc = SMEM + (cur << 15);
        char* Vc = Kc + 16384;

        // ---- S^T = K Q^T: 8 A-reads, 16 MFMAs (A reused across 2 q-tiles) ----
        f32x4 s00 = {0.f,0.f,0.f,0.f}, s10 = {0.f,0.f,0.f,0.f};
        f32x4 s01 = {0.f,0.f,0.f,0.f}, s11 = {0.f,0.f,0.f,0.f};
        #pragma unroll
        for (int m = 0; m < 4; ++m) {
            short8 f0 = *(const short8*)(Kc + ((kb0 + (m << 6)) ^ kkey));
            short8 f1 = *(const short8*)(Kc + ((kb1 + (m << 6)) ^ kkey));
            s00 = __builtin_amdgcn_mfma_f32_16x16x32_bf16(f0, qb[m][0], s00, 0, 0, 0);
            s10 = __builtin_amdgcn_mfma_f32_16x16x32_bf16(f1, qb[m][0], s10, 0, 0, 0);
            s01 = __builtin_amdgcn_mfma_f32_16x16x32_bf16(f0, qb[m][1], s01, 0, 0, 0);
            s11 = __builtin_amdgcn_mfma_f32_16x16x32_bf16(f1, qb[m][1], s11, 0, 0, 0);
        }

        // ---- causal mask (residual tiles only) ----
        if (u >= 64) {
            int base = (u - 64) * 64 + 32 * th + 8 * g;
            int q0g = 32 * qh + r, q1g = q0g + 16;
            #pragma unroll
            for (int reg = 0; reg < 4; ++reg) {
                if (base + reg     > 64 + q0g) s00[reg] = -1e30f;
                if (base + 4 + reg > 64 + q0g) s10[reg] = -1e30f;
                if (base + reg     > 64 + q1g) s01[reg] = -1e30f;
                if (base + 4 + reg > 64 + q1g) s11[reg] = -1e30f;
            }
        }

        // ---- HOISTED stage of unit u+1: dequant VALU issues under QK-MFMA
        //      latency; DS writes drain under the softmax VALU phase. ----
        if (u + 1 < uhi) {
            char* Kn = SMEM + ((cur ^ 1) << 15);
            char* Vn = Kn + 16384;
            if (u + 1 < 64) {
                stage_quant(Kn, Vn);
                if (u + 2 < uhi && u + 2 < 64) pfb();
            } else {
                stage_resid(u + 1 - 64, Kn, Vn);
            }
        }

        // ---- softmax: wave-uniform m_run, no cross-lane in common path ----
        {
            float mx = fmaxf(
                fmaxf(fmaxf(fmaxf(s00[0], s00[1]), fmaxf(s00[2], s00[3])),
                      fmaxf(fmaxf(s10[0], s10[1]), fmaxf(s10[2], s10[3]))),
                fmaxf(fmaxf(fmaxf(s01[0], s01[1]), fmaxf(s01[2], s01[3])),
                      fmaxf(fmaxf(s11[0], s11[1]), fmaxf(s11[2], s11[3]))));
            if (!__all(mx <= m_run + DEFER_THR)) {
                float wmx = mx;
                #pragma unroll
                for (int off = 1; off < 64; off <<= 1)
                    wmx = fmaxf(wmx, __shfl_xor(wmx, off));
                float mnew = fmaxf(m_run, wmx);
                float alpha = __expf(m_run - mnew);   // exp(-inf)=0 first time
                lr0 *= alpha; lr1 *= alpha;
                m_run = mnew;
                #pragma unroll
                for (int nd = 0; nd < 4; ++nd) {
                    #pragma unroll
                    for (int reg = 0; reg < 4; ++reg) {
                        o[nd][0][reg] *= alpha;
                        o[nd][1][reg] *= alpha;
                    }
                }
            }
            float p00[4], p10[4], p01[4], p11[4];
            #pragma unroll
            for (int reg = 0; reg < 4; ++reg) {
                p00[reg] = __expf(s00[reg] - m_run);
                p10[reg] = __expf(s10[reg] - m_run);
                p01[reg] = __expf(s01[reg] - m_run);
                p11[reg] = __expf(s11[reg] - m_run);
            }
            lr0 += ((p00[0]+p00[1]) + (p00[2]+p00[3])) + ((p10[0]+p10[1]) + (p10[2]+p10[3]));
            lr1 += ((p01[0]+p01[1]) + (p01[2]+p01[3])) + ((p11[0]+p11[1]) + (p11[2]+p11[3]));

            short8 pf0 = pack8(make_float4(p00[0], p00[1], p00[2], p00[3]),
                               make_float4(p10[0], p10[1], p10[2], p10[3]));
            short8 pf1 = pack8(make_float4(p01[0], p01[1], p01[2], p01[3]),
                               make_float4(p11[0], p11[1], p11[2], p11[3]));

            // ---- O^T = V^T P^T: 4 A-reads (d-half ds), 8 MFMAs ----
            #pragma unroll
            for (int nd = 0; nd < 4; ++nd) {
                int d = 64 * ds + 16 * nd + r;
                int vkey = ((d & 7) ^ ((d >> 3) & 7)) << 4;
                short8 vb = *(const short8*)(Vc + (((d << 7) + 64 * th + 16 * g) ^ vkey));
                o[nd][0] = __builtin_amdgcn_mfma_f32_16x16x32_bf16(vb, pf0, o[nd][0], 0, 0, 0);
                o[nd][1] = __builtin_amdgcn_mfma_f32_16x16x32_bf16(vb, pf1, o[nd][1], 0, 0, 0);
            }
        }

        __syncthreads();   // buf(cur) consumed; buf(cur^1) staged
    }

    // ---- epilogue: merge th-halves via LDS overlay, transpose, write ----
    lr0 += __shfl_xor(lr0, 16); lr0 += __shfl_xor(lr0, 32);
    lr1 += __shfl_xor(lr1, 16); lr1 += __shfl_xor(lr1, 32);

    float* Osc = (float*)SMEM;                  // overlay [128d][64q] f32 = 32 KB
    float* mB  = (float*)(SMEM + 32768);        // [64]
    float* lB  = (float*)(SMEM + 33024);        // [64]
    if (th == 1) {
        #pragma unroll
        for (int nd = 0; nd < 4; ++nd) {
            #pragma unroll
            for (int qt = 0; qt < 2; ++qt) {
                #pragma unroll
                for (int reg = 0; reg < 4; ++reg)
                    Osc[(64 * ds + 16 * nd + 4 * g + reg) * 64 + (32 * qh + 16 * qt + r)]
                        = o[nd][qt][reg];
            }
        }
        if (g == 0 && ds == 0) {
            mB[32 * qh + r]      = m_run;  lB[32 * qh + r]      = lr0;
            mB[32 * qh + 16 + r] = m_run;  lB[32 * qh + 16 + r] = lr1;
        }
    }
    __syncthreads();
    if (th == 0) {
        float lrq[2] = { lr0, lr1 };
        float w1q[2], w2q[2], nrm[2];
        #pragma unroll
        for (int qt = 0; qt < 2; ++qt) {
            int q_ = 32 * qh + 16 * qt + r;
            float m2 = mB[q_], l2 = lB[q_];
            float M  = fmaxf(m_run, m2);
            float w1 = __expf(m_run - M), w2 = __expf(m2 - M);
            float lt = lrq[qt] * w1 + l2 * w2;
            w1q[qt] = w1; w2q[qt] = w2;
            nrm[qt] = (NS == 1) ? (1.0f / lt) : 1.0f;
            if (NS > 1 && g == 0 && ds == 0) {
                float* wsM = ws + (size_t)128 * NS * 8192;
                float* wsL = wsM + (size_t)128 * NS * 64;
                wsM[pb * 64 + q_] = M;
                wsL[pb * 64 + q_] = lt;
            }
        }
        #pragma unroll
        for (int nd = 0; nd < 4; ++nd) {
            #pragma unroll
            for (int qt = 0; qt < 2; ++qt) {
                #pragma unroll
                for (int reg = 0; reg < 4; ++reg) {
                    int d  = 64 * ds + 16 * nd + 4 * g + reg;
                    int q_ = 32 * qh + 16 * qt + r;
                    o[nd][qt][reg] = (o[nd][qt][reg] * w1q[qt]
                                      + Osc[d * 64 + q_] * w2q[qt]) * nrm[qt];
                }
            }
        }
    }
    __syncthreads();   // all d-major reads done before q-major overwrite
    if (th == 0) {
        #pragma unroll
        for (int nd = 0; nd < 4; ++nd) {
            #pragma unroll
            for (int qt = 0; qt < 2; ++qt) {
                #pragma unroll
                for (int reg = 0; reg < 4; ++reg)
                    Osc[(32 * qh + 16 * qt + r) * 128 + 64 * ds + 16 * nd + 4 * g + reg]
                        = o[nd][qt][reg];
            }
        }
    }
    __syncthreads();
    {   // coalesced copy [64][128] f32 -> destination
        float* dst = (NS == 1) ? (out + (size_t)bh * 8192) : (ws + (size_t)pb * 8192);
        int row = tid >> 3;
        int c   = tid & 7;
        #pragma unroll
        for (int cc = 0; cc < 4; ++cc) {
            int col4 = (c + 8 * cc) * 4;
            f32x4 v = *(const f32x4*)(Osc + row * 128 + col4);
            *(f32x4*)(dst + (size_t)row * 128 + col4) = v;
        }
    }
}

template<int NS>
__global__ __launch_bounds__(256, 1)
void kivi_combine(const float* __restrict__ ws, float* __restrict__ out)
{
    const int bh  = blockIdx.x;
    const int tid = threadIdx.x;
    const int q   = tid >> 2;
    const int dq  = (tid & 3) << 5;
    const float* wsO = ws;
    const float* wsM = ws + (size_t)128 * NS * 8192;
    const float* wsL = wsM + (size_t)128 * NS * 64;

    float mv[NS];
    float M = -INFINITY;
    #pragma unroll
    for (int sp = 0; sp < NS; ++sp) {
        mv[sp] = wsM[(bh * NS + sp) * 64 + q];
        M = fmaxf(M, mv[sp]);
    }
    float lt = 0.f;
    #pragma unroll
    for (int sp = 0; sp < NS; ++sp) {
        mv[sp] = __expf(mv[sp] - M);
        lt += wsL[(bh * NS + sp) * 64 + q] * mv[sp];
    }
    float inv = 1.0f / lt;
    float4 acc[8];
    #pragma unroll
    for (int i = 0; i < 8; ++i) acc[i] = make_float4(0.f, 0.f, 0.f, 0.f);
    #pragma unroll
    for (int sp = 0; sp < NS; ++sp) {
        const float* Op = wsO + ((size_t)(bh * NS + sp)) * 8192 + q * 128 + dq;
        float wgt = mv[sp];
        #pragma unroll
        for (int i = 0; i < 8; ++i) {
            float4 f = *(const float4*)(Op + 4 * i);
            acc[i].x += f.x * wgt; acc[i].y += f.y * wgt;
            acc[i].z += f.z * wgt; acc[i].w += f.w * wgt;
        }
    }
    float* op = out + (size_t)bh * 8192 + q * 128 + dq;
    #pragma unroll
    for (int i = 0; i < 8; ++i) {
        float4 f = make_float4(acc[i].x * inv, acc[i].y * inv, acc[i].z * inv, acc[i].w * inv);
        *(float4*)(op + 4 * i) = f;
    }
}

extern "C" void kernel_launch(void* const* d_in, const int* in_sizes, int n_in,
                              void* d_out, int out_size, void* d_ws, size_t ws_size,
                              hipStream_t stream) {
    const float* qry    = (const float*)d_in[0];
    const int*   kcode  = (const int*)  d_in[1];
    const float* kscale = (const float*)d_in[2];
    const float* kmn    = (const float*)d_in[3];
    const float* kfull  = (const float*)d_in[4];
    const int*   vcode  = (const int*)  d_in[5];
    const float* vscale = (const float*)d_in[6];
    const float* vmn    = (const float*)d_in[7];
    const float* vfull  = (const float*)d_in[8];
    float* out = (float*)d_out;
    float* ws  = (float*)d_ws;

    const size_t needPerNS = ((size_t)128 * 8192 + 2 * 128 * 64) * sizeof(float);
    if (ws_size >= 4 * needPerNS) {
        kivi_attn<4><<<dim3(Bn * Hn * 4), dim3(NTHREADS), 0, stream>>>(
            qry, kcode, kscale, kmn, kfull, vcode, vscale, vmn, vfull, out, ws);
        kivi_combine<4><<<dim3(Bn * Hn), dim3(256), 0, stream>>>(ws, out);
    } else if (ws_size >= 2 * needPerNS) {
        kivi_attn<2><<<dim3(Bn * Hn * 2), dim3(NTHREADS), 0, stream>>>(
            qry, kcode, kscale, kmn, kfull, vcode, vscale, vmn, vfull, out, ws);
        kivi_combine<2><<<dim3(Bn * Hn), dim3(256), 0, stream>>>(ws, out);
    } else {
        kivi_attn<1><<<dim3(Bn * Hn), dim3(NTHREADS), 0, stream>>>(
            qry, kcode, kscale, kmn, kfull, vcode, vscale, vmn, vfull, out, ws);
    }
}

// Round 17
// 104.628 us; speedup vs baseline: 1.0140x; 1.0140x over previous
//
#include <hip/hip_runtime.h>
#include <hip/hip_bf16.h>
#include <cmath>

#define Bn 4
#define Hn 32
#define Qn 64
#define Dn 128
#define Tn 4096
#define Rn 128
#define NTHREADS 512
#define SCALE_QK 0.08838834764831845f
#define NUNITS 66      // 64 quantized KV tiles of 64 + 2 residual tiles
#define DEFER_THR 8.0f

typedef __attribute__((ext_vector_type(8))) short short8;
typedef __attribute__((ext_vector_type(4))) float f32x4;

__device__ __forceinline__ unsigned pk2(float a, float b) {
    __hip_bfloat162 h = __float22bfloat162_rn(make_float2(a, b));
    unsigned u; __builtin_memcpy(&u, &h, 4); return u;
}
__device__ __forceinline__ short8 pack8(float4 f0, float4 f1) {
    unsigned u[4] = { pk2(f0.x,f0.y), pk2(f0.z,f0.w), pk2(f1.x,f1.y), pk2(f1.z,f1.w) };
    short8 s; __builtin_memcpy(&s, u, 16); return s;
}
__device__ __forceinline__ float dq1(unsigned c, int j, float s, float m) {
    return (float)((c >> (4 * j)) & 15u) * s + m;
}

// FINAL (R15 restore, measured 104.70 us; R16's stage-hoist regressed).
// Plateau arithmetic: per unit-block ~3.8k cyc = DS 2.3k (fragment-minimal
// 96 b128 reads + 64 b64 writes + ~650 conflict) + VALU 1.5k (KIVI dequant +
// exp) + MFMA 0.24k ~= 108% of wall -> sum-of-pipes limit, phases overlapped.
// 8 fat waves: th = w&1 (t-half), qh = (w>>1)&1 (32 q), ds = (w>>2)&1 (PV
// d-half). K A-frag reads reused across 2 q-tiles. b64 staged writes,
// duty-split tid<256 = K, tid>=256 = V. Stage placed post-PV (stage-early
// contends with QK reads on the DS pipe -- R16 evidence).
// LDS: dbuf 2x32KB (K [64t][128d] 256B rows, key ((t>>3)&3|(t&1)<<2)<<4;
//      V^T [128d][64t] 128B rows, key ((d&7)^((d>>3)&7))<<4)  -- R9-verified.
template<int NS>
__global__ __launch_bounds__(NTHREADS, 2)
void kivi_attn(const float* __restrict__ qry,
               const int*   __restrict__ kcode,
               const float* __restrict__ kscale,
               const float* __restrict__ kmn,
               const float* __restrict__ kfull,
               const int*   __restrict__ vcode,
               const float* __restrict__ vscale,
               const float* __restrict__ vmn,
               const float* __restrict__ vfull,
               float* __restrict__ out,
               float* __restrict__ ws)
{
    __shared__ __align__(16) char SMEM[65536];

    const int tid = threadIdx.x;
    const int bh  = blockIdx.x / NS;
    const int sp  = blockIdx.x % NS;
    const int pb  = bh * NS + sp;
    const int ulo = (sp * NUNITS) / NS;
    const int uhi = ((sp + 1) * NUNITS) / NS;

    const int*   kc  = kcode  + (size_t)bh * (Dn * (Tn / 8));
    const float* ksc = kscale + (size_t)bh * (Dn * (Tn / 32));
    const float* kmm = kmn    + (size_t)bh * (Dn * (Tn / 32));
    const float* kf  = kfull  + (size_t)bh * (Rn * Dn);
    const int*   vc  = vcode  + (size_t)bh * (Tn * (Dn / 8));
    const float* vsc = vscale + (size_t)bh * (Tn * (Dn / 32));
    const float* vmm = vmn    + (size_t)bh * (Tn * (Dn / 32));
    const float* vf  = vfull  + (size_t)bh * (Rn * Dn);

    const int w    = tid >> 6;        // wave 0..7
    const int lane = tid & 63;
    const int th   = w & 1;           // t-half
    const int qh   = (w >> 1) & 1;    // q-half (32 q)
    const int ds   = (w >> 2) & 1;    // PV d-half
    const int g    = lane >> 4;
    const int r    = lane & 15;

    // stage duty: tid<256 K, tid>=256 V
    const bool kduty = (tid < 256);
    const int  tw  = tid & 7,  dg = (tid >> 3) & 31;   // K: t-octet, d-quad
    const int  vwd = tid & 15, tq = (tid >> 4) & 15;   // V: d-octet, t-quad

    // ---- Q B-fragments (scale baked in): 2 q-tiles, cols q = 32qh + 16qt + r ----
    short8 qb[4][2];
    #pragma unroll
    for (int qt = 0; qt < 2; ++qt) {
        const float* qrow = qry + ((size_t)bh * Qn + (32 * qh + 16 * qt + r)) * Dn;
        #pragma unroll
        for (int m = 0; m < 4; ++m) {
            float4 f0 = *(const float4*)(qrow + m * 32 + 8 * g);
            float4 f1 = *(const float4*)(qrow + m * 32 + 8 * g + 4);
            f0.x *= SCALE_QK; f0.y *= SCALE_QK; f0.z *= SCALE_QK; f0.w *= SCALE_QK;
            f1.x *= SCALE_QK; f1.y *= SCALE_QK; f1.z *= SCALE_QK; f1.w *= SCALE_QK;
            qb[m][qt] = pack8(f0, f1);
        }
    }

    // ---- permuted QK A-row mapping (R9-verified): s0/s1 regs <-> t = 32th+8g+{0..7}
    const int t0p  = 32 * th + 8 * (r >> 2) + (r & 3);
    const int kkey = (((r >> 2) | ((r & 1) << 2)) << 4);   // key(t0p) == key(t0p+4)
    const int kb0  = (t0p << 8) + (g << 4);
    const int kb1  = kb0 + (4 << 8);

    f32x4 o[4][2];
    #pragma unroll
    for (int nd = 0; nd < 4; ++nd) {
        o[nd][0] = (f32x4){0.f, 0.f, 0.f, 0.f};
        o[nd][1] = (f32x4){0.f, 0.f, 0.f, 0.f};
    }
    float m_run = -INFINITY;          // wave-uniform
    float lr0 = 0.f, lr1 = 0.f;       // per-lane partials (g-reduced at epilogue)

    // ---- union'd prefetch (4 codes + 4 scales + 4 mins per duty) ----
    const int* cp; const float* scp; const float* mnp;
    int cstr, sstr, cinc, sinc;
    if (kduty) {
        cp  = kc  + (size_t)(4 * dg) * (Tn / 8)  + ulo * 8 + tw;
        scp = ksc + (size_t)(4 * dg) * (Tn / 32) + ulo * 2 + (tw >> 2);
        mnp = kmm + (size_t)(4 * dg) * (Tn / 32) + ulo * 2 + (tw >> 2);
        cstr = Tn / 8;  sstr = Tn / 32;  cinc = 8;  sinc = 2;
    } else {
        cp  = vc  + ((size_t)ulo * 64 + 4 * tq) * (Dn / 8)  + vwd;
        scp = vsc + ((size_t)ulo * 64 + 4 * tq) * (Dn / 32) + (vwd >> 2);
        mnp = vmm + ((size_t)ulo * 64 + 4 * tq) * (Dn / 32) + (vwd >> 2);
        cstr = Dn / 8;  sstr = Dn / 32;
        cinc = 64 * (Dn / 8);  sinc = 64 * (Dn / 32);
    }
    unsigned cc4[4]; float sc4[4], mn4[4];
    auto pfb = [&]() {
        #pragma unroll
        for (int i = 0; i < 4; ++i) {
            cc4[i] = (unsigned)cp[i * cstr];
            sc4[i] = scp[i * sstr];
            mn4[i] = mnp[i * sstr];
        }
        cp += cinc; scp += sinc; mnp += sinc;
    };

    auto stage_quant = [&](char* Kb, char* Vb) {
        if (kduty) {
            // 4 d (=4dg..+3) x 8 t (octet tw): one b64 (4 bf16 along d) per t
            #pragma unroll
            for (int j = 0; j < 8; ++j) {
                int t = 8 * tw + j;
                int key = (((tw & 3) | ((j & 1) << 2)) << 4);
                float v0 = dq1(cc4[0], j, sc4[0], mn4[0]);
                float v1 = dq1(cc4[1], j, sc4[1], mn4[1]);
                float v2 = dq1(cc4[2], j, sc4[2], mn4[2]);
                float v3 = dq1(cc4[3], j, sc4[3], mn4[3]);
                unsigned long long pk = (unsigned long long)pk2(v0, v1)
                                      | ((unsigned long long)pk2(v2, v3) << 32);
                *(unsigned long long*)(Kb + (((t << 8) + 8 * dg) ^ key)) = pk;
            }
        } else {
            // 8 d (octet vwd) x 4 t (=4tq..+3): one b64 (4 bf16 along t) per d
            #pragma unroll
            for (int i = 0; i < 8; ++i) {
                int d = 8 * vwd + i;
                int key = ((i ^ (vwd & 7)) << 4);
                float v0 = dq1(cc4[0], i, sc4[0], mn4[0]);
                float v1 = dq1(cc4[1], i, sc4[1], mn4[1]);
                float v2 = dq1(cc4[2], i, sc4[2], mn4[2]);
                float v3 = dq1(cc4[3], i, sc4[3], mn4[3]);
                unsigned long long pk = (unsigned long long)pk2(v0, v1)
                                      | ((unsigned long long)pk2(v2, v3) << 32);
                *(unsigned long long*)(Vb + (((d << 7) + 8 * tq) ^ key)) = pk;
            }
        }
    };
    auto stage_resid = [&](int rt, char* Kb, char* Vb) {
        {   // K residual fp32 (R9-verbatim, 512 threads)
            int t = tid & 63, dgr = tid >> 6;
            const float* kr = kf + (size_t)(rt * 64 + t) * Dn + dgr * 16;
            int key = (((t >> 3) & 3) | ((t & 1) << 2)) << 4;
            #pragma unroll
            for (int s2 = 0; s2 < 2; ++s2) {
                float4 f0 = *(const float4*)(kr + s2 * 8);
                float4 f1 = *(const float4*)(kr + s2 * 8 + 4);
                *(short8*)(Kb + (((t << 8) + dgr * 32 + s2 * 16) ^ key)) = pack8(f0, f1);
            }
        }
        {   // V residual fp32 transposed gather (R9-verbatim)
            int d = tid & 127, t4 = tid >> 7;
            const float* vr = vf + (size_t)(rt * 64 + t4 * 16) * Dn + d;
            int key = ((d & 7) ^ ((d >> 3) & 7)) << 4;
            #pragma unroll
            for (int s2 = 0; s2 < 2; ++s2) {
                float4 f0, f1;
                f0.x = vr[(size_t)(s2 * 8 + 0) * Dn]; f0.y = vr[(size_t)(s2 * 8 + 1) * Dn];
                f0.z = vr[(size_t)(s2 * 8 + 2) * Dn]; f0.w = vr[(size_t)(s2 * 8 + 3) * Dn];
                f1.x = vr[(size_t)(s2 * 8 + 4) * Dn]; f1.y = vr[(size_t)(s2 * 8 + 5) * Dn];
                f1.z = vr[(size_t)(s2 * 8 + 6) * Dn]; f1.w = vr[(size_t)(s2 * 8 + 7) * Dn];
                *(short8*)(Vb + (((d << 7) + t4 * 32 + s2 * 16) ^ key)) = pack8(f0, f1);
            }
        }
    };

    // ---- prologue: stage unit ulo into buf0 (ulo < 64 always for NS<=4) ----
    pfb();
    stage_quant(SMEM, SMEM + 16384);
    if (ulo + 1 < uhi && ulo + 1 < 64) pfb();
    __syncthreads();

    for (int u = ulo; u < uhi; ++u) {
        const int cur = (u - ulo) & 1;
        char* Kc = SMEM + (cur << 15);
        char* Vc = Kc + 16384;

        // ---- S^T = K Q^T: 8 A-reads, 16 MFMAs (A reused across 2 q-tiles) ----
        f32x4 s00 = {0.f,0.f,0.f,0.f}, s10 = {0.f,0.f,0.f,0.f};
        f32x4 s01 = {0.f,0.f,0.f,0.f}, s11 = {0.f,0.f,0.f,0.f};
        #pragma unroll
        for (int m = 0; m < 4; ++m) {
            short8 f0 = *(const short8*)(Kc + ((kb0 + (m << 6)) ^ kkey));
            short8 f1 = *(const short8*)(Kc + ((kb1 + (m << 6)) ^ kkey));
            s00 = __builtin_amdgcn_mfma_f32_16x16x32_bf16(f0, qb[m][0], s00, 0, 0, 0);
            s10 = __builtin_amdgcn_mfma_f32_16x16x32_bf16(f1, qb[m][0], s10, 0, 0, 0);
            s01 = __builtin_amdgcn_mfma_f32_16x16x32_bf16(f0, qb[m][1], s01, 0, 0, 0);
            s11 = __builtin_amdgcn_mfma_f32_16x16x32_bf16(f1, qb[m][1], s11, 0, 0, 0);
        }

        // ---- causal mask (residual tiles only) ----
        if (u >= 64) {
            int base = (u - 64) * 64 + 32 * th + 8 * g;
            int q0g = 32 * qh + r, q1g = q0g + 16;
            #pragma unroll
            for (int reg = 0; reg < 4; ++reg) {
                if (base + reg     > 64 + q0g) s00[reg] = -1e30f;
                if (base + 4 + reg > 64 + q0g) s10[reg] = -1e30f;
                if (base + reg     > 64 + q1g) s01[reg] = -1e30f;
                if (base + 4 + reg > 64 + q1g) s11[reg] = -1e30f;
            }
        }

        // ---- softmax: wave-uniform m_run, no cross-lane in common path ----
        {
            float mx = fmaxf(
                fmaxf(fmaxf(fmaxf(s00[0], s00[1]), fmaxf(s00[2], s00[3])),
                      fmaxf(fmaxf(s10[0], s10[1]), fmaxf(s10[2], s10[3]))),
                fmaxf(fmaxf(fmaxf(s01[0], s01[1]), fmaxf(s01[2], s01[3])),
                      fmaxf(fmaxf(s11[0], s11[1]), fmaxf(s11[2], s11[3]))));
            if (!__all(mx <= m_run + DEFER_THR)) {
                float wmx = mx;
                #pragma unroll
                for (int off = 1; off < 64; off <<= 1)
                    wmx = fmaxf(wmx, __shfl_xor(wmx, off));
                float mnew = fmaxf(m_run, wmx);
                float alpha = __expf(m_run - mnew);   // exp(-inf)=0 first time
                lr0 *= alpha; lr1 *= alpha;
                m_run = mnew;
                #pragma unroll
                for (int nd = 0; nd < 4; ++nd) {
                    #pragma unroll
                    for (int reg = 0; reg < 4; ++reg) {
                        o[nd][0][reg] *= alpha;
                        o[nd][1][reg] *= alpha;
                    }
                }
            }
            float p00[4], p10[4], p01[4], p11[4];
            #pragma unroll
            for (int reg = 0; reg < 4; ++reg) {
                p00[reg] = __expf(s00[reg] - m_run);
                p10[reg] = __expf(s10[reg] - m_run);
                p01[reg] = __expf(s01[reg] - m_run);
                p11[reg] = __expf(s11[reg] - m_run);
            }
            lr0 += ((p00[0]+p00[1]) + (p00[2]+p00[3])) + ((p10[0]+p10[1]) + (p10[2]+p10[3]));
            lr1 += ((p01[0]+p01[1]) + (p01[2]+p01[3])) + ((p11[0]+p11[1]) + (p11[2]+p11[3]));

            short8 pf0 = pack8(make_float4(p00[0], p00[1], p00[2], p00[3]),
                               make_float4(p10[0], p10[1], p10[2], p10[3]));
            short8 pf1 = pack8(make_float4(p01[0], p01[1], p01[2], p01[3]),
                               make_float4(p11[0], p11[1], p11[2], p11[3]));

            // ---- O^T = V^T P^T: 4 A-reads (d-half ds), 8 MFMAs ----
            #pragma unroll
            for (int nd = 0; nd < 4; ++nd) {
                int d = 64 * ds + 16 * nd + r;
                int vkey = ((d & 7) ^ ((d >> 3) & 7)) << 4;
                short8 vb = *(const short8*)(Vc + (((d << 7) + 64 * th + 16 * g) ^ vkey));
                o[nd][0] = __builtin_amdgcn_mfma_f32_16x16x32_bf16(vb, pf0, o[nd][0], 0, 0, 0);
                o[nd][1] = __builtin_amdgcn_mfma_f32_16x16x32_bf16(vb, pf1, o[nd][1], 0, 0, 0);
            }
        }

        // ---- stage next unit into the other buffer ----
        if (u + 1 < uhi) {
            char* Kn = SMEM + ((cur ^ 1) << 15);
            char* Vn = Kn + 16384;
            if (u + 1 < 64) {
                stage_quant(Kn, Vn);
                if (u + 2 < uhi && u + 2 < 64) pfb();
            } else {
                stage_resid(u + 1 - 64, Kn, Vn);
            }
        }
        __syncthreads();
    }

    // ---- epilogue: merge th-halves via LDS overlay, transpose, write ----
    // (loop's final __syncthreads already orders all PV reads before overlay)
    lr0 += __shfl_xor(lr0, 16); lr0 += __shfl_xor(lr0, 32);
    lr1 += __shfl_xor(lr1, 16); lr1 += __shfl_xor(lr1, 32);

    float* Osc = (float*)SMEM;                  // overlay [128d][64q] f32 = 32 KB
    float* mB  = (float*)(SMEM + 32768);        // [64]
    float* lB  = (float*)(SMEM + 33024);        // [64]
    if (th == 1) {
        #pragma unroll
        for (int nd = 0; nd < 4; ++nd) {
            #pragma unroll
            for (int qt = 0; qt < 2; ++qt) {
                #pragma unroll
                for (int reg = 0; reg < 4; ++reg)
                    Osc[(64 * ds + 16 * nd + 4 * g + reg) * 64 + (32 * qh + 16 * qt + r)]
                        = o[nd][qt][reg];
            }
        }
        if (g == 0 && ds == 0) {
            mB[32 * qh + r]      = m_run;  lB[32 * qh + r]      = lr0;
            mB[32 * qh + 16 + r] = m_run;  lB[32 * qh + 16 + r] = lr1;
        }
    }
    __syncthreads();
    if (th == 0) {
        float lrq[2] = { lr0, lr1 };
        float w1q[2], w2q[2], nrm[2];
        #pragma unroll
        for (int qt = 0; qt < 2; ++qt) {
            int q_ = 32 * qh + 16 * qt + r;
            float m2 = mB[q_], l2 = lB[q_];
            float M  = fmaxf(m_run, m2);
            float w1 = __expf(m_run - M), w2 = __expf(m2 - M);
            float lt = lrq[qt] * w1 + l2 * w2;
            w1q[qt] = w1; w2q[qt] = w2;
            nrm[qt] = (NS == 1) ? (1.0f / lt) : 1.0f;
            if (NS > 1 && g == 0 && ds == 0) {
                float* wsM = ws + (size_t)128 * NS * 8192;
                float* wsL = wsM + (size_t)128 * NS * 64;
                wsM[pb * 64 + q_] = M;
                wsL[pb * 64 + q_] = lt;
            }
        }
        #pragma unroll
        for (int nd = 0; nd < 4; ++nd) {
            #pragma unroll
            for (int qt = 0; qt < 2; ++qt) {
                #pragma unroll
                for (int reg = 0; reg < 4; ++reg) {
                    int d  = 64 * ds + 16 * nd + 4 * g + reg;
                    int q_ = 32 * qh + 16 * qt + r;
                    o[nd][qt][reg] = (o[nd][qt][reg] * w1q[qt]
                                      + Osc[d * 64 + q_] * w2q[qt]) * nrm[qt];
                }
            }
        }
    }
    __syncthreads();   // all d-major reads done before q-major overwrite
    if (th == 0) {
        #pragma unroll
        for (int nd = 0; nd < 4; ++nd) {
            #pragma unroll
            for (int qt = 0; qt < 2; ++qt) {
                #pragma unroll
                for (int reg = 0; reg < 4; ++reg)
                    Osc[(32 * qh + 16 * qt + r) * 128 + 64 * ds + 16 * nd + 4 * g + reg]
                        = o[nd][qt][reg];
            }
        }
    }
    __syncthreads();
    {   // coalesced copy [64][128] f32 -> destination
        float* dst = (NS == 1) ? (out + (size_t)bh * 8192) : (ws + (size_t)pb * 8192);
        int row = tid >> 3;
        int c   = tid & 7;
        #pragma unroll
        for (int cc = 0; cc < 4; ++cc) {
            int col4 = (c + 8 * cc) * 4;
            f32x4 v = *(const f32x4*)(Osc + row * 128 + col4);
            *(f32x4*)(dst + (size_t)row * 128 + col4) = v;
        }
    }
}

template<int NS>
__global__ __launch_bounds__(256, 1)
void kivi_combine(const float* __restrict__ ws, float* __restrict__ out)
{
    const int bh  = blockIdx.x;
    const int tid = threadIdx.x;
    const int q   = tid >> 2;
    const int dq  = (tid & 3) << 5;
    const float* wsO = ws;
    const float* wsM = ws + (size_t)128 * NS * 8192;
    const float* wsL = wsM + (size_t)128 * NS * 64;

    float mv[NS];
    float M = -INFINITY;
    #pragma unroll
    for (int sp = 0; sp < NS; ++sp) {
        mv[sp] = wsM[(bh * NS + sp) * 64 + q];
        M = fmaxf(M, mv[sp]);
    }
    float lt = 0.f;
    #pragma unroll
    for (int sp = 0; sp < NS; ++sp) {
        mv[sp] = __expf(mv[sp] - M);
        lt += wsL[(bh * NS + sp) * 64 + q] * mv[sp];
    }
    float inv = 1.0f / lt;
    float4 acc[8];
    #pragma unroll
    for (int i = 0; i < 8; ++i) acc[i] = make_float4(0.f, 0.f, 0.f, 0.f);
    #pragma unroll
    for (int sp = 0; sp < NS; ++sp) {
        const float* Op = wsO + ((size_t)(bh * NS + sp)) * 8192 + q * 128 + dq;
        float wgt = mv[sp];
        #pragma unroll
        for (int i = 0; i < 8; ++i) {
            float4 f = *(const float4*)(Op + 4 * i);
            acc[i].x += f.x * wgt; acc[i].y += f.y * wgt;
            acc[i].z += f.z * wgt; acc[i].w += f.w * wgt;
        }
    }
    float* op = out + (size_t)bh * 8192 + q * 128 + dq;
    #pragma unroll
    for (int i = 0; i < 8; ++i) {
        float4 f = make_float4(acc[i].x * inv, acc[i].y * inv, acc[i].z * inv, acc[i].w * inv);
        *(float4*)(op + 4 * i) = f;
    }
}

extern "C" void kernel_launch(void* const* d_in, const int* in_sizes, int n_in,
                              void* d_out, int out_size, void* d_ws, size_t ws_size,
                              hipStream_t stream) {
    const float* qry    = (const float*)d_in[0];
    const int*   kcode  = (const int*)  d_in[1];
    const float* kscale = (const float*)d_in[2];
    const float* kmn    = (const float*)d_in[3];
    const float* kfull  = (const float*)d_in[4];
    const int*   vcode  = (const int*)  d_in[5];
    const float* vscale = (const float*)d_in[6];
    const float* vmn    = (const float*)d_in[7];
    const float* vfull  = (const float*)d_in[8];
    float* out = (float*)d_out;
    float* ws  = (float*)d_ws;

    const size_t needPerNS = ((size_t)128 * 8192 + 2 * 128 * 64) * sizeof(float);
    if (ws_size >= 4 * needPerNS) {
        kivi_attn<4><<<dim3(Bn * Hn * 4), dim3(NTHREADS), 0, stream>>>(
            qry, kcode, kscale, kmn, kfull, vcode, vscale, vmn, vfull, out, ws);
        kivi_combine<4><<<dim3(Bn * Hn), dim3(256), 0, stream>>>(ws, out);
    } else if (ws_size >= 2 * needPerNS) {
        kivi_attn<2><<<dim3(Bn * Hn * 2), dim3(NTHREADS), 0, stream>>>(
            qry, kcode, kscale, kmn, kfull, vcode, vscale, vmn, vfull, out, ws);
        kivi_combine<2><<<dim3(Bn * Hn), dim3(256), 0, stream>>>(ws, out);
    } else {
        kivi_attn<1><<<dim3(Bn * Hn), dim3(NTHREADS), 0, stream>>>(
            qry, kcode, kscale, kmn, kfull, vcode, vscale, vmn, vfull, out, ws);
    }
}